// Round 6
// baseline (8223.693 us; speedup 1.0000x reference)
//
#include <hip/hip_runtime.h>
#include <stdint.h>

typedef unsigned short u16;
typedef unsigned int   u32;
using f32x4  = __attribute__((ext_vector_type(4))) float;
using bf16x8 = __attribute__((ext_vector_type(8))) short;   // 8 bf16 codes (4 VGPRs)

// ---------------- fp32 -> bf16 (RNE) conversion, vectorized ----------------
__device__ __forceinline__ u16 f2bf(float f) {
  union { float f; u32 u; } c; c.f = f;
  return (u16)((c.u + 0x7FFFu + ((c.u >> 16) & 1u)) >> 16);
}

__global__ void cvt_f32_bf16(const float* __restrict__ in, u16* __restrict__ out, int n8) {
  int i = blockIdx.x * blockDim.x + threadIdx.x;
  const int stride = gridDim.x * blockDim.x;
  for (; i < n8; i += stride) {
    float4 v0 = reinterpret_cast<const float4*>(in)[2 * i];
    float4 v1 = reinterpret_cast<const float4*>(in)[2 * i + 1];
    uint4 o;
    o.x = (u32)f2bf(v0.x) | ((u32)f2bf(v0.y) << 16);
    o.y = (u32)f2bf(v0.z) | ((u32)f2bf(v0.w) << 16);
    o.z = (u32)f2bf(v1.x) | ((u32)f2bf(v1.y) << 16);
    o.w = (u32)f2bf(v1.z) | ((u32)f2bf(v1.w) << 16);
    reinterpret_cast<uint4*>(out)[i] = o;
  }
}

// async global->LDS, 16B per lane, dest = wave-uniform base + lane*16
#define GLD_LDS16(SRC, DST)                                      \
  __builtin_amdgcn_global_load_lds(                              \
      (const __attribute__((address_space(1))) void*)(SRC),      \
      (__attribute__((address_space(3))) void*)(DST), 16, 0, 0)

#define SCHED0() __builtin_amdgcn_sched_barrier(0)
#define BAR()    __builtin_amdgcn_s_barrier()
#define PRIO(x)  __builtin_amdgcn_s_setprio(x)

// ------------- 256x256 bf16 GEMM, BK=32, 64KiB LDS -> 2 blocks/CU -------------
// 8 waves (2M x 4N), per-wave 128x64 output (8x4 16x16x32 frags), 32 MFMA/wave/tile.
// The 2 independent blocks per CU de-lockstep the SIMDs: one block's barrier/stage
// window is filled by the other block's MFMA stream (m114 co-scheduling).
// LDS tile [256 rows][32 cols]: row = 64B = 4 slots of 16B.
// Swizzle: phys_slot = kslot ^ ((row>>1)&3)  (exact 2-way bank aliasing = free).
// Staged via inverse-swizzled global source, linear gload_lds dest (both-sides rule).
// Per K-tile, 2 phases (all MFMA operands pre-read in earlier phases):
//   p0: BAR | MFMA mh0*bf(t) | read afB=A-mh1(t) from cur     | vmcnt(0)
//   p1: BAR | MFMA mh1*bf(t) | read afA=A-mh0(t+1), bf(t+1) from cur^1
//       | stage A(t+2),B(t+2)->cur (dead regions)
__global__ __launch_bounds__(512, 4)
void gemm256_bk32(const u16* __restrict__ A,   // [M][K] bf16
                  const u16* __restrict__ B,   // [N][K] bf16
                  const float* __restrict__ scale_p,
                  const float* __restrict__ bias,
                  float* __restrict__ C,       // [M][N] fp32
                  int Nn, int Kk, int NT) {
  __shared__ u16 lds[2][2][256 * 32];  // [buf][A/B][256 rows x 32 cols] = 64 KiB

  const int tid  = threadIdx.x;
  const int lane = tid & 63;
  const int wave = tid >> 6;       // 0..7
  const int wr = wave >> 2;        // 0..1 (M)
  const int wc = wave & 3;         // 0..3 (N)

  // T1: XCD-aware swizzle (gridDim.x == 2048, divisible by 8)
  const int bid = blockIdx.x;
  const int cpx = gridDim.x >> 3;
  const int wg  = (bid & 7) * cpx + (bid >> 3);
  const int mt = wg / NT, nt = wg % NT;
  const int m0 = mt * 256, n0 = nt * 256;

  // staging: per gload instr, 64 lanes = 16 rows x 64B; lane l -> row l>>2, slot l&3
  const int srow = lane >> 2;
  const int ss   = (lane & 3) ^ ((lane >> 3) & 3);   // inverse-swizzled source k-slot
  const int r16  = lane & 15;
  const int kq   = lane >> 4;

  // per-thread global staging bases (row = j*128 + wave*16 + srow, col = kt*32 + ss*8)
  const u16* ga = A + ((size_t)m0 + wave * 16 + srow) * Kk + ss * 8;
  const u16* gb = B + ((size_t)n0 + wave * 16 + srow) * Kk + ss * 8;

  // fragment read offsets: row*32 + (kq ^ ((row>>1)&3))*8 ; frag step = 16*32 = 512
  const int aoff = (wr * 128 + r16) * 32 + (kq ^ ((r16 >> 1) & 3)) * 8;
  const int boff = (wc * 64  + r16) * 32 + (kq ^ ((r16 >> 1) & 3)) * 8;

  f32x4 acc[8][4];
#pragma unroll
  for (int i = 0; i < 8; ++i)
#pragma unroll
    for (int j = 0; j < 4; ++j)
      acc[i][j] = (f32x4){0.f, 0.f, 0.f, 0.f};

  bf16x8 afA[4], afB[4];   // A frags mh0 / mh1 (roles fixed across tiles)
  bf16x8 bfA[4], bfB[4];   // B frags, alternate by tile parity

  // stage one operand tile (16KB = 2 gload/thread): op (0=A,1=B) -> lds[bfi], k-tile kt
#define STAGE32(bfi_, op_, kt_) do {                                            \
    const u16* _g = ((op_) ? gb : ga) + (size_t)(kt_) * 32;                     \
    u16* _d = &lds[bfi_][op_][wave * 16 * 32];                                  \
    GLD_LDS16(_g,                       _d);                                    \
    GLD_LDS16(_g + (size_t)128 * Kk,    _d + 128 * 32);                         \
  } while (0)

#define LDA32(AF_, la_, mh_) do {                                               \
    _Pragma("unroll") for (int _i = 0; _i < 4; ++_i)                            \
      AF_[_i] = *reinterpret_cast<const bf16x8*>(                               \
          (la_) + aoff + ((mh_) * 4 + _i) * 512);                               \
  } while (0)

#define LDB32(BF_, lb_) do {                                                    \
    _Pragma("unroll") for (int _n = 0; _n < 4; ++_n)                            \
      BF_[_n] = *reinterpret_cast<const bf16x8*>((lb_) + boff + _n * 512);      \
  } while (0)

#define MFMA16(mh_, AF_, BF_)                                                   \
  _Pragma("unroll") for (int i = 0; i < 4; ++i)                                 \
  _Pragma("unroll") for (int n = 0; n < 4; ++n)                                 \
    acc[(mh_) * 4 + i][n] = __builtin_amdgcn_mfma_f32_16x16x32_bf16(            \
        AF_[i], BF_[n], acc[(mh_) * 4 + i][n], 0, 0, 0)

  const int KT = Kk >> 5;   // K/32 = 128

  // ---- prologue: t0->buf0, t1->buf1; drain t0; pre-read t0 frags ----
  STAGE32(0, 0, 0); STAGE32(0, 1, 0);
  STAGE32(1, 0, 1); STAGE32(1, 1, 1);
  asm volatile("s_waitcnt vmcnt(4)" ::: "memory");
  SCHED0(); BAR(); SCHED0();
  LDA32(afA, (const u16*)&lds[0][0][0], 0);
  LDB32(bfA, (const u16*)&lds[0][1][0]);

  // BF0_ = bf(t) (both phases), BF1_ = bf(t+1) dest (read at p1 from cur^1)
#define TILE(t_, CUR_, BF0_, BF1_) do {                                         \
    const u16* la  = &lds[CUR_][0][0];                                          \
    const u16* la1 = &lds[(CUR_) ^ 1][0][0];                                    \
    const u16* lb1 = &lds[(CUR_) ^ 1][1][0];                                    \
    const int kt2 = ((t_) + 2 < KT) ? (t_) + 2 : KT - 1;                        \
    /* p0 */                                                                    \
    SCHED0(); BAR(); SCHED0();                                                  \
    PRIO(1); MFMA16(0, afA, BF0_); PRIO(0);                                     \
    LDA32(afB, la, 1);                                                          \
    asm volatile("s_waitcnt vmcnt(0)" ::: "memory");                            \
    /* p1 */                                                                    \
    SCHED0(); BAR(); SCHED0();                                                  \
    PRIO(1); MFMA16(1, afB, BF0_); PRIO(0);                                     \
    LDA32(afA, la1, 0);                                                         \
    LDB32(BF1_, lb1);                                                           \
    STAGE32(CUR_, 0, kt2);                                                      \
    STAGE32(CUR_, 1, kt2);                                                      \
  } while (0)

  for (int kt = 0; kt < KT; kt += 2) {
    TILE(kt,     0, bfA, bfB);
    TILE(kt + 1, 1, bfB, bfA);
  }

  // ---- epilogue: out = acc*scale + bias ----
  const float sc = scale_p[0];
  float bv[4];
#pragma unroll
  for (int ni = 0; ni < 4; ++ni) bv[ni] = bias[n0 + wc * 64 + ni * 16 + r16];
#pragma unroll
  for (int mi = 0; mi < 8; ++mi) {
#pragma unroll
    for (int r = 0; r < 4; ++r) {
      // C/D layout (16x16x32): col = lane&15, row = (lane>>4)*4 + reg
      const int row = m0 + wr * 128 + mi * 16 + kq * 4 + r;
      float* cp = C + (size_t)row * Nn + (n0 + wc * 64 + r16);
#pragma unroll
      for (int ni = 0; ni < 4; ++ni)
        cp[ni * 16] = acc[mi][ni][r] * sc + bv[ni];
    }
  }
#undef STAGE32
#undef LDA32
#undef LDB32
#undef MFMA16
#undef TILE
}

extern "C" void kernel_launch(void* const* d_in, const int* in_sizes, int n_in,
                              void* d_out, int out_size, void* d_ws, size_t ws_size,
                              hipStream_t stream) {
  (void)n_in; (void)out_size; (void)ws_size;
  const float* x  = (const float*)d_in[0];   // [M][K] fp32
  const float* w  = (const float*)d_in[1];   // [N][K] fp32 (fp8-representable values)
  const float* sc = (const float*)d_in[2];   // [1]
  const float* bs = (const float*)d_in[3];   // [N]
  float* out = (float*)d_out;                // [M][N] fp32

  const int N = in_sizes[3];        // 16384
  const int K = in_sizes[1] / N;    // 4096
  const int M = in_sizes[0] / K;    // 8192

  u16* xb = (u16*)d_ws;                      // [M][K] bf16  (64 MB)
  u16* wb = xb + (size_t)M * K;              // [N][K] bf16  (128 MB)

  cvt_f32_bf16<<<2048, 256, 0, stream>>>(x, xb, (M * K) / 8);
  cvt_f32_bf16<<<2048, 256, 0, stream>>>(w, wb, (N * K) / 8);

  const int NT = N / 256;
  const int nwg = (M / 256) * NT;            // 2048, % 8 == 0
  gemm256_bk32<<<nwg, 512, 0, stream>>>(xb, wb, sc, bs, out, N, K, NT);
}

// Round 7
// 1142.739 us; speedup vs baseline: 7.1965x; 7.1965x over previous
//
#include <hip/hip_runtime.h>
#include <stdint.h>

typedef unsigned short u16;
typedef unsigned int   u32;
using f32x4  = __attribute__((ext_vector_type(4))) float;
using bf16x8 = __attribute__((ext_vector_type(8))) short;   // 8 bf16 codes (4 VGPRs)

// ---------------- fp32 -> bf16 (RNE) conversion, vectorized ----------------
__device__ __forceinline__ u16 f2bf(float f) {
  union { float f; u32 u; } c; c.f = f;
  return (u16)((c.u + 0x7FFFu + ((c.u >> 16) & 1u)) >> 16);
}

__global__ void cvt_f32_bf16(const float* __restrict__ in, u16* __restrict__ out, int n8) {
  int i = blockIdx.x * blockDim.x + threadIdx.x;
  const int stride = gridDim.x * blockDim.x;
  for (; i < n8; i += stride) {
    float4 v0 = reinterpret_cast<const float4*>(in)[2 * i];
    float4 v1 = reinterpret_cast<const float4*>(in)[2 * i + 1];
    uint4 o;
    o.x = (u32)f2bf(v0.x) | ((u32)f2bf(v0.y) << 16);
    o.y = (u32)f2bf(v0.z) | ((u32)f2bf(v0.w) << 16);
    o.z = (u32)f2bf(v1.x) | ((u32)f2bf(v1.y) << 16);
    o.w = (u32)f2bf(v1.z) | ((u32)f2bf(v1.w) << 16);
    reinterpret_cast<uint4*>(out)[i] = o;
  }
}

// async global->LDS, 16B per lane, dest = wave-uniform base + lane*16
#define GLD_LDS16(SRC, DST)                                      \
  __builtin_amdgcn_global_load_lds(                              \
      (const __attribute__((address_space(1))) void*)(SRC),      \
      (__attribute__((address_space(3))) void*)(DST), 16, 0, 0)

#define SCHED0() __builtin_amdgcn_sched_barrier(0)
#define SGB(m_, n_) __builtin_amdgcn_sched_group_barrier(m_, n_, 0)
#define BAR()    __builtin_amdgcn_s_barrier()
#define PRIO(x)  __builtin_amdgcn_s_setprio(x)

// ------- 256x256 bf16 GEMM, BK=32, triple-buffered LDS (96 KiB), T19 interleave -------
// 8 waves (2M x 4N), per-wave 128x64 output (8x4 16x16x32 frags), 32 MFMA/wave/K-tile.
// LDS tile [256 rows][32 cols], row = 64B = 4 slots of 16B.
// Swizzle: phys_slot = kslot ^ ((row>>1)&3) (2-way bank aliasing = free; 0 conflicts
// verified r6). Staged via inverse-swizzled global source, linear gload_lds dest.
// Fully register-pipelined 2-phase tile; staging 3 TILES AHEAD into buf[t%3]:
//   p0: BAR | MFMA mh0*bf(t) ||interleaved|| read afB=A-mh1(t)      | vmcnt(4)
//   p1: BAR | MFMA mh1*bf(t) ||interleaved|| read afA=A-mh0(t+1), bf(t+1) from buf[(t+1)%3]
//       || stage A,B(t+3)->buf[t%3]
// Gate ledger: each p1 issues 4 gloads; at t.p0 outstanding = {(t-2).p1: 4, (t-1).p1: 4};
// vmcnt(4) drains (t-2).p1 = tile t+1 data (3 phases ~1600cyc old -> free), exactly what
// t.p1's ds_reads need. T19 sched_group_barrier forces 4xMFMA : reads : stage emission
// so read/stage issue slots hide under the MFMA stream (all interleaved ops dep-free).
__global__ __launch_bounds__(512, 2)
void gemm256_3buf(const u16* __restrict__ A,   // [M][K] bf16
                  const u16* __restrict__ B,   // [N][K] bf16
                  const float* __restrict__ scale_p,
                  const float* __restrict__ bias,
                  float* __restrict__ C,       // [M][N] fp32
                  int Nn, int Kk, int NT) {
  __shared__ u16 lds[3][2][256 * 32];  // [buf][A/B][256 rows x 32 cols] = 96 KiB

  const int tid  = threadIdx.x;
  const int lane = tid & 63;
  const int wave = tid >> 6;       // 0..7
  const int wr = wave >> 2;        // 0..1 (M)
  const int wc = wave & 3;         // 0..3 (N)

  // T1: XCD-aware swizzle (gridDim.x == 2048, divisible by 8)
  const int bid = blockIdx.x;
  const int cpx = gridDim.x >> 3;
  const int wg  = (bid & 7) * cpx + (bid >> 3);
  const int mt = wg / NT, nt = wg % NT;
  const int m0 = mt * 256, n0 = nt * 256;

  // staging: per gload instr, 64 lanes = 16 rows x 64B; lane l -> row l>>2, slot l&3
  const int srow = lane >> 2;
  const int ss   = (lane & 3) ^ ((lane >> 3) & 3);   // inverse-swizzled source k-slot
  const int r16  = lane & 15;
  const int kq   = lane >> 4;

  // per-thread global staging bases (row = j*128 + wave*16 + srow, col = kt*32 + ss*8)
  const u16* ga = A + ((size_t)m0 + wave * 16 + srow) * Kk + ss * 8;
  const u16* gb = B + ((size_t)n0 + wave * 16 + srow) * Kk + ss * 8;

  // fragment read offsets: row*32 + (kq ^ ((row>>1)&3))*8 ; frag step = 16*32 = 512
  const int aoff = (wr * 128 + r16) * 32 + (kq ^ ((r16 >> 1) & 3)) * 8;
  const int boff = (wc * 64  + r16) * 32 + (kq ^ ((r16 >> 1) & 3)) * 8;

  f32x4 acc[8][4];
#pragma unroll
  for (int i = 0; i < 8; ++i)
#pragma unroll
    for (int j = 0; j < 4; ++j)
      acc[i][j] = (f32x4){0.f, 0.f, 0.f, 0.f};

  bf16x8 afA[4], afB[4];   // A frags mh0 / mh1
  bf16x8 bfP[4], bfQ[4];   // B frag sets, alternate by tile parity

  // stage one operand tile (16KB = 2 gload/thread): op (0=A,1=B) -> lds[bfi], k-tile kt
#define STAGE32(bfi_, op_, kt_) do {                                            \
    const u16* _g = ((op_) ? gb : ga) + (size_t)(kt_) * 32;                     \
    u16* _d = &lds[bfi_][op_][wave * 16 * 32];                                  \
    GLD_LDS16(_g,                       _d);                                    \
    GLD_LDS16(_g + (size_t)128 * Kk,    _d + 128 * 32);                         \
  } while (0)

#define LDA32(AF_, la_, mh_) do {                                               \
    _Pragma("unroll") for (int _i = 0; _i < 4; ++_i)                            \
      AF_[_i] = *reinterpret_cast<const bf16x8*>(                               \
          (la_) + aoff + ((mh_) * 4 + _i) * 512);                               \
  } while (0)

#define LDB32(BF_, lb_) do {                                                    \
    _Pragma("unroll") for (int _n = 0; _n < 4; ++_n)                            \
      BF_[_n] = *reinterpret_cast<const bf16x8*>((lb_) + boff + _n * 512);      \
  } while (0)

#define MFMA16(mh_, AF_, BF_)                                                   \
  _Pragma("unroll") for (int i = 0; i < 4; ++i)                                 \
  _Pragma("unroll") for (int n = 0; n < 4; ++n)                                 \
    acc[(mh_) * 4 + i][n] = __builtin_amdgcn_mfma_f32_16x16x32_bf16(            \
        AF_[i], BF_[n], acc[(mh_) * 4 + i][n], 0, 0, 0)

  // T19 templates (masks: MFMA=0x8, DS_READ=0x100, VMEM_READ=0x20)
#define SGB_P0() do {                                                           \
    _Pragma("unroll") for (int _q = 0; _q < 4; ++_q) {                          \
      SGB(0x8, 4); SGB(0x100, 1);                                               \
    } } while (0)
#define SGB_P1() do {                                                           \
    _Pragma("unroll") for (int _q = 0; _q < 4; ++_q) {                          \
      SGB(0x8, 4); SGB(0x100, 2); SGB(0x20, 1);                                 \
    } } while (0)

  const int KT = Kk >> 5;   // K/32 = 128

  // ---- prologue: tiles 0,1,2 -> bufs 0,1,2; drain t0; pre-read t0 frags ----
  STAGE32(0, 0, 0); STAGE32(0, 1, 0);
  STAGE32(1, 0, 1); STAGE32(1, 1, 1);
  STAGE32(2, 0, 2); STAGE32(2, 1, 2);
  asm volatile("s_waitcnt vmcnt(8)" ::: "memory");
  SCHED0(); BAR(); SCHED0();
  LDA32(afA, (const u16*)&lds[0][0][0], 0);
  LDB32(bfP, (const u16*)&lds[0][1][0]);

  // B0_ = t%3 (literal), B1_ = (t+1)%3 (literal); BF0_ = bf(t), BF1_ = bf(t+1) dest
#define TILE(t_, B0_, B1_, BF0_, BF1_) do {                                     \
    const u16* laC = &lds[B0_][0][0];                                           \
    const u16* laN = &lds[B1_][0][0];                                           \
    const u16* lbN = &lds[B1_][1][0];                                           \
    const int kt3 = ((t_) + 3 < KT) ? (t_) + 3 : KT - 1;                        \
    /* p0 */                                                                    \
    SCHED0(); BAR(); SCHED0();                                                  \
    PRIO(1);                                                                    \
    MFMA16(0, afA, BF0_);                                                       \
    LDA32(afB, laC, 1);                                                         \
    SGB_P0();                                                                   \
    PRIO(0);                                                                    \
    SCHED0();                                                                   \
    asm volatile("s_waitcnt vmcnt(4)" ::: "memory");                            \
    /* p1 */                                                                    \
    SCHED0(); BAR(); SCHED0();                                                  \
    PRIO(1);                                                                    \
    MFMA16(1, afB, BF0_);                                                       \
    LDA32(afA, laN, 0);                                                         \
    LDB32(BF1_, lbN);                                                           \
    STAGE32(B0_, 0, kt3);                                                       \
    STAGE32(B0_, 1, kt3);                                                       \
    SGB_P1();                                                                   \
    PRIO(0);                                                                    \
  } while (0)

  // period-6 pattern (buf %3 x B-parity %2); KT=128 -> 126 in loop + 2 tail tiles
  for (int t = 0; t < KT - 2; t += 6) {
    TILE(t + 0, 0, 1, bfP, bfQ);
    TILE(t + 1, 1, 2, bfQ, bfP);
    TILE(t + 2, 2, 0, bfP, bfQ);
    TILE(t + 3, 0, 1, bfQ, bfP);
    TILE(t + 4, 1, 2, bfP, bfQ);
    TILE(t + 5, 2, 0, bfQ, bfP);
  }
  TILE(KT - 2, 0, 1, bfP, bfQ);
  TILE(KT - 1, 1, 2, bfQ, bfP);

  // ---- epilogue: out = acc*scale + bias ----
  const float sc = scale_p[0];
  float bv[4];
#pragma unroll
  for (int ni = 0; ni < 4; ++ni) bv[ni] = bias[n0 + wc * 64 + ni * 16 + r16];
#pragma unroll
  for (int mi = 0; mi < 8; ++mi) {
#pragma unroll
    for (int r = 0; r < 4; ++r) {
      // C/D layout (16x16x32): col = lane&15, row = (lane>>4)*4 + reg
      const int row = m0 + wr * 128 + mi * 16 + kq * 4 + r;
      float* cp = C + (size_t)row * Nn + (n0 + wc * 64 + r16);
#pragma unroll
      for (int ni = 0; ni < 4; ++ni)
        cp[ni * 16] = acc[mi][ni][r] * sc + bv[ni];
    }
  }
#undef STAGE32
#undef LDA32
#undef LDB32
#undef MFMA16
#undef SGB_P0
#undef SGB_P1
#undef TILE
}

extern "C" void kernel_launch(void* const* d_in, const int* in_sizes, int n_in,
                              void* d_out, int out_size, void* d_ws, size_t ws_size,
                              hipStream_t stream) {
  (void)n_in; (void)out_size; (void)ws_size;
  const float* x  = (const float*)d_in[0];   // [M][K] fp32
  const float* w  = (const float*)d_in[1];   // [N][K] fp32 (fp8-representable values)
  const float* sc = (const float*)d_in[2];   // [1]
  const float* bs = (const float*)d_in[3];   // [N]
  float* out = (float*)d_out;                // [M][N] fp32

  const int N = in_sizes[3];        // 16384
  const int K = in_sizes[1] / N;    // 4096
  const int M = in_sizes[0] / K;    // 8192

  u16* xb = (u16*)d_ws;                      // [M][K] bf16  (64 MB)
  u16* wb = xb + (size_t)M * K;              // [N][K] bf16  (128 MB)

  cvt_f32_bf16<<<2048, 256, 0, stream>>>(x, xb, (M * K) / 8);
  cvt_f32_bf16<<<2048, 256, 0, stream>>>(w, wb, (N * K) / 8);

  const int NT = N / 256;
  const int nwg = (M / 256) * NT;            // 2048, % 8 == 0
  gemm256_3buf<<<nwg, 512, 0, stream>>>(xb, wb, sc, bs, out, N, K, NT);
}

// Round 8
// 723.297 us; speedup vs baseline: 11.3697x; 1.5799x over previous
//
#include <hip/hip_runtime.h>
#include <stdint.h>

typedef unsigned int u32;
using i32x4 = __attribute__((ext_vector_type(4))) int;

// async global->LDS, 16B per lane, dest = wave-uniform base + lane*16
#define GLD_LDS16(SRC, DST)                                      \
  __builtin_amdgcn_global_load_lds(                              \
      (const __attribute__((address_space(1))) void*)(SRC),      \
      (__attribute__((address_space(3))) void*)(DST), 16, 0, 0)

#define SCHED0() __builtin_amdgcn_sched_barrier(0)
#define BAR()    __builtin_amdgcn_s_barrier()
#define PRIO(x)  __builtin_amdgcn_s_setprio(x)

// ---------- pass 1: per-row symmetric int8 quant (x rows, then w rows) ----------
// one block per row of K=4096 fp32; 256 threads x 16 elems.
__global__ __launch_bounds__(256)
void quant_rows(const float* __restrict__ x, const float* __restrict__ w,
                signed char* __restrict__ xq, signed char* __restrict__ wq,
                float* __restrict__ sx, float* __restrict__ sw,
                int Mrows, int totRows, int K) {
  __shared__ float red[4];
  for (int row = blockIdx.x; row < totRows; row += gridDim.x) {
    const bool isx = row < Mrows;
    const float* src = isx ? x + (size_t)row * K : w + (size_t)(row - Mrows) * K;
    const float4* s4 = reinterpret_cast<const float4*>(src) + threadIdx.x * 4;
    float4 v[4];
#pragma unroll
    for (int g = 0; g < 4; ++g) v[g] = s4[g];
    float am = 0.f;
#pragma unroll
    for (int g = 0; g < 4; ++g)
      am = fmaxf(am, fmaxf(fmaxf(fabsf(v[g].x), fabsf(v[g].y)),
                           fmaxf(fabsf(v[g].z), fabsf(v[g].w))));
#pragma unroll
    for (int m = 1; m <= 32; m <<= 1) am = fmaxf(am, __shfl_xor(am, m));
    if ((threadIdx.x & 63) == 0) red[threadIdx.x >> 6] = am;
    __syncthreads();
    am = fmaxf(fmaxf(red[0], red[1]), fmaxf(red[2], red[3]));
    const float s   = am > 0.f ? am * (1.f / 127.f) : 1.f;
    const float inv = am > 0.f ? 127.f / am : 0.f;
    u32 pk[4];
#pragma unroll
    for (int g = 0; g < 4; ++g) {
      const float* vp = reinterpret_cast<const float*>(&v[g]);
      u32 p = 0;
#pragma unroll
      for (int e = 0; e < 4; ++e) {
        int q = (int)rintf(vp[e] * inv);
        q = q < -127 ? -127 : (q > 127 ? 127 : q);
        p |= ((u32)(q & 0xff)) << (8 * e);
      }
      pk[g] = p;
    }
    signed char* dst = (isx ? xq + (size_t)row * K : wq + (size_t)(row - Mrows) * K)
                       + threadIdx.x * 16;
    *reinterpret_cast<uint4*>(dst) = make_uint4(pk[0], pk[1], pk[2], pk[3]);
    if (threadIdx.x == 0) { if (isx) sx[row] = s; else sw[row - Mrows] = s; }
    __syncthreads();
  }
}

// ---------- pass 2: int8 GEMM, C = (A_q @ B_q^T) * sx[m] * sw[n] * wscale + bias ----------
// 256x256 tile, BK=64 (i8), 8 waves (2M x 4N), per-wave 128x64 = 8x4 16x16x64 frags,
// 32 MFMA/wave/K-tile. LDS [2 buf][A/B][256 rows x 64B] = 64 KiB.
// Row = 64B = 4 slots of 16B; swizzle phys_slot = kslot ^ ((row>>1)&3)
// (2-way bank aliasing = free; 0 conflicts verified round 6, identical byte pattern).
// Register-pipelined 2-phase tile (all MFMA operands ds_read in an earlier phase):
//   p0: BAR | MFMA mh0*B(t) | read afB=A-mh1(t) | stage B(t+2)->cur | vmcnt(2)
//   p1: BAR | MFMA mh1*B(t) | read afA=A-mh0(t+1), B(t+1) from buf^1 | stage A(t+2)->cur
// Gate ledger: outstanding at p0 gate = {B(t+1):2, A(t+1):2, B(t+2):2}=6 -> vmcnt(2)
// drains exactly the t+1 data needed by p1's pre-reads (>=1 phase old, L3-resident).
__global__ __launch_bounds__(512, 2)
void gemm_i8(const signed char* __restrict__ A,   // [M][K] i8
             const signed char* __restrict__ B,   // [N][K] i8
             const float* __restrict__ sx,        // [M]
             const float* __restrict__ sw,        // [N]
             const float* __restrict__ wscale_p,  // [1]
             const float* __restrict__ bias,      // [N]
             float* __restrict__ C,               // [M][N] fp32
             int Nn, int Kk, int NT) {
  __shared__ signed char lds[2][2][256 * 64];

  const int tid  = threadIdx.x;
  const int lane = tid & 63;
  const int wave = tid >> 6;       // 0..7
  const int wr = wave >> 2;        // 0..1 (M)
  const int wc = wave & 3;         // 0..3 (N)

  // T1: XCD-aware swizzle (gridDim.x == 2048, divisible by 8)
  const int bid = blockIdx.x;
  const int cpx = gridDim.x >> 3;
  const int wg  = (bid & 7) * cpx + (bid >> 3);
  const int mt = wg / NT, nt = wg % NT;
  const int m0 = mt * 256, n0 = nt * 256;

  // staging: per gload instr, 64 lanes = 16 rows x 64B; lane l -> row l>>2, slot l&3
  const int srow = lane >> 2;
  const int ss   = (lane & 3) ^ ((lane >> 3) & 3);   // inverse-swizzled source slot
  const int r16  = lane & 15;
  const int kq   = lane >> 4;

  // per-thread global staging bases (wave covers rows wave*32 .. wave*32+31)
  const signed char* ga = A + ((size_t)m0 + wave * 32 + srow) * Kk + ss * 16;
  const signed char* gb = B + ((size_t)n0 + wave * 32 + srow) * Kk + ss * 16;

  // fragment byte offsets: row*64 + (kq ^ ((row>>1)&3))*16 ; frag step = 16*64 = 1024
  const int aoff = (wr * 128 + r16) * 64 + ((kq ^ ((r16 >> 1) & 3)) << 4);
  const int boff = (wc * 64  + r16) * 64 + ((kq ^ ((r16 >> 1) & 3)) << 4);

  i32x4 acc[8][4];
#pragma unroll
  for (int i = 0; i < 8; ++i)
#pragma unroll
    for (int j = 0; j < 4; ++j)
      acc[i][j] = (i32x4){0, 0, 0, 0};

  i32x4 afA[4], afB[4];   // A frags mh0 / mh1
  i32x4 bP[4], bQ[4];     // B frag sets, alternate by tile parity

  // stage one operand tile (16KB = 2 gload/wave): op (0=A,1=B) -> lds[bfi], k-tile kt
#define STAGEI(bfi_, op_, kt_) do {                                             \
    const signed char* _g = ((op_) ? gb : ga) + (size_t)(kt_) * 64;             \
    signed char* _d = &lds[bfi_][op_][wave * 32 * 64];                          \
    GLD_LDS16(_g,                    _d);                                       \
    GLD_LDS16(_g + (size_t)16 * Kk,  _d + 16 * 64);                             \
  } while (0)

#define LDAI(AF_, la_, mh_) do {                                                \
    _Pragma("unroll") for (int _i = 0; _i < 4; ++_i)                            \
      AF_[_i] = *reinterpret_cast<const i32x4*>(                                \
          (la_) + aoff + ((mh_) * 4 + _i) * 1024);                              \
  } while (0)

#define LDBI(BF_, lb_) do {                                                     \
    _Pragma("unroll") for (int _n = 0; _n < 4; ++_n)                            \
      BF_[_n] = *reinterpret_cast<const i32x4*>((lb_) + boff + _n * 1024);      \
  } while (0)

#define MFMAI(mh_, AF_, BF_)                                                    \
  _Pragma("unroll") for (int i = 0; i < 4; ++i)                                 \
  _Pragma("unroll") for (int n = 0; n < 4; ++n)                                 \
    acc[(mh_) * 4 + i][n] = __builtin_amdgcn_mfma_i32_16x16x64_i8(              \
        AF_[i], BF_[n], acc[(mh_) * 4 + i][n], 0, 0, 0)

  const int KT = Kk >> 6;   // K/64 = 64

  // ---- prologue: t0->buf0, t1->buf1; drain t0; pre-read t0 frags ----
  STAGEI(0, 0, 0); STAGEI(0, 1, 0);
  STAGEI(1, 0, 1); STAGEI(1, 1, 1);
  asm volatile("s_waitcnt vmcnt(4)" ::: "memory");
  SCHED0(); BAR(); SCHED0();
  LDAI(afA, (const signed char*)&lds[0][0][0], 0);
  LDBI(bP,  (const signed char*)&lds[0][1][0]);

#define TILEI(t_, CUR_, B0_, B1_) do {                                          \
    const signed char* laC = &lds[CUR_][0][0];                                  \
    const signed char* laN = &lds[(CUR_) ^ 1][0][0];                            \
    const signed char* lbN = &lds[(CUR_) ^ 1][1][0];                            \
    const int kt2 = ((t_) + 2 < KT) ? (t_) + 2 : KT - 1;                        \
    /* p0 */                                                                    \
    SCHED0(); BAR(); SCHED0();                                                  \
    PRIO(1); MFMAI(0, afA, B0_); PRIO(0);                                       \
    LDAI(afB, laC, 1);                                                          \
    STAGEI(CUR_, 1, kt2);                                                       \
    SCHED0();                                                                   \
    asm volatile("s_waitcnt vmcnt(2)" ::: "memory");                            \
    /* p1 */                                                                    \
    SCHED0(); BAR(); SCHED0();                                                  \
    PRIO(1); MFMAI(1, afB, B0_); PRIO(0);                                       \
    LDAI(afA, laN, 0);                                                          \
    LDBI(B1_, lbN);                                                             \
    STAGEI(CUR_, 0, kt2);                                                       \
  } while (0)

  for (int t = 0; t < KT; t += 2) {
    TILEI(t,     0, bP, bQ);
    TILEI(t + 1, 1, bQ, bP);
  }

  // ---- epilogue: out = acc * sx[row] * (sw[col]*wscale) + bias ----
  const float wsc = wscale_p[0];
  float cw[4], bv[4];
#pragma unroll
  for (int ni = 0; ni < 4; ++ni) {
    const int col = n0 + wc * 64 + ni * 16 + r16;
    cw[ni] = sw[col] * wsc;
    bv[ni] = bias[col];
  }
#pragma unroll
  for (int mi = 0; mi < 8; ++mi) {
#pragma unroll
    for (int r = 0; r < 4; ++r) {
      // C/D layout (16x16 shapes, dtype-independent): col = lane&15, row = (lane>>4)*4 + reg
      const int row = m0 + wr * 128 + mi * 16 + kq * 4 + r;
      const float sxr = sx[row];
      float* cp = C + (size_t)row * Nn + (n0 + wc * 64 + r16);
#pragma unroll
      for (int ni = 0; ni < 4; ++ni)
        cp[ni * 16] = (float)acc[mi][ni][r] * (sxr * cw[ni]) + bv[ni];
    }
  }
#undef STAGEI
#undef LDAI
#undef LDBI
#undef MFMAI
#undef TILEI
}

extern "C" void kernel_launch(void* const* d_in, const int* in_sizes, int n_in,
                              void* d_out, int out_size, void* d_ws, size_t ws_size,
                              hipStream_t stream) {
  (void)n_in; (void)out_size; (void)ws_size;
  const float* x  = (const float*)d_in[0];   // [M][K] fp32
  const float* w  = (const float*)d_in[1];   // [N][K] fp32 (fp8-representable values)
  const float* sc = (const float*)d_in[2];   // [1]
  const float* bs = (const float*)d_in[3];   // [N]
  float* out = (float*)d_out;                // [M][N] fp32

  const int N = in_sizes[3];        // 16384
  const int K = in_sizes[1] / N;    // 4096
  const int M = in_sizes[0] / K;    // 8192

  signed char* xq = (signed char*)d_ws;            // [M][K] i8  (32 MB)
  signed char* wq = xq + (size_t)M * K;            // [N][K] i8  (64 MB)
  float* sxp = (float*)(wq + (size_t)N * K);       // [M]
  float* swp = sxp + M;                            // [N]

  quant_rows<<<M + N, 256, 0, stream>>>(x, w, xq, wq, sxp, swp, M, M + N, K);

  const int NT = N / 256;
  const int nwg = (M / 256) * NT;                  // 2048, % 8 == 0
  gemm_i8<<<nwg, 512, 0, stream>>>(xq, wq, sxp, swp, sc, bs, out, N, K, NT);
}

// Round 9
// 630.911 us; speedup vs baseline: 13.0346x; 1.1464x over previous
//
#include <hip/hip_runtime.h>
#include <stdint.h>

typedef unsigned int u32;
using i32x4 = __attribute__((ext_vector_type(4))) int;

// async global->LDS, 16B per lane, dest = wave-uniform base + lane*16
#define GLD_LDS16(SRC, DST)                                      \
  __builtin_amdgcn_global_load_lds(                              \
      (const __attribute__((address_space(1))) void*)(SRC),      \
      (__attribute__((address_space(3))) void*)(DST), 16, 0, 0)

#define SCHED0() __builtin_amdgcn_sched_barrier(0)
#define BAR()    __builtin_amdgcn_s_barrier()
#define PRIO(x)  __builtin_amdgcn_s_setprio(x)

// ---------- pass 1: per-row symmetric int8 quant (x rows, then w rows) ----------
__global__ __launch_bounds__(256)
void quant_rows(const float* __restrict__ x, const float* __restrict__ w,
                signed char* __restrict__ xq, signed char* __restrict__ wq,
                float* __restrict__ sx, float* __restrict__ sw,
                int Mrows, int totRows, int K) {
  __shared__ float red[4];
  for (int row = blockIdx.x; row < totRows; row += gridDim.x) {
    const bool isx = row < Mrows;
    const float* src = isx ? x + (size_t)row * K : w + (size_t)(row - Mrows) * K;
    const float4* s4 = reinterpret_cast<const float4*>(src) + threadIdx.x * 4;
    float4 v[4];
#pragma unroll
    for (int g = 0; g < 4; ++g) v[g] = s4[g];
    float am = 0.f;
#pragma unroll
    for (int g = 0; g < 4; ++g)
      am = fmaxf(am, fmaxf(fmaxf(fabsf(v[g].x), fabsf(v[g].y)),
                           fmaxf(fabsf(v[g].z), fabsf(v[g].w))));
#pragma unroll
    for (int m = 1; m <= 32; m <<= 1) am = fmaxf(am, __shfl_xor(am, m));
    if ((threadIdx.x & 63) == 0) red[threadIdx.x >> 6] = am;
    __syncthreads();
    am = fmaxf(fmaxf(red[0], red[1]), fmaxf(red[2], red[3]));
    const float s   = am > 0.f ? am * (1.f / 127.f) : 1.f;
    const float inv = am > 0.f ? 127.f / am : 0.f;
    u32 pk[4];
#pragma unroll
    for (int g = 0; g < 4; ++g) {
      const float* vp = reinterpret_cast<const float*>(&v[g]);
      u32 p = 0;
#pragma unroll
      for (int e = 0; e < 4; ++e) {
        int q = (int)rintf(vp[e] * inv);
        q = q < -127 ? -127 : (q > 127 ? 127 : q);
        p |= ((u32)(q & 0xff)) << (8 * e);
      }
      pk[g] = p;
    }
    signed char* dst = (isx ? xq + (size_t)row * K : wq + (size_t)(row - Mrows) * K)
                       + threadIdx.x * 16;
    *reinterpret_cast<uint4*>(dst) = make_uint4(pk[0], pk[1], pk[2], pk[3]);
    if (threadIdx.x == 0) { if (isx) sx[row] = s; else sw[row - Mrows] = s; }
    __syncthreads();
  }
}

// ---------- pass 2: int8 GEMM BK=128, C = (A_q @ B_q^T) * sx[m]*sw[n]*wscale + bias ----------
// 256x256 tile, BK=128 (i8), 8 waves (2M x 4N), per-wave 128x64 = 8x4 16x16x64 frags,
// 64 MFMA/wave/K-tile in 4 clusters of 16 (mh0ks0, mh1ks0, mh0ks1, mh1ks1).
// LDS [2 buf][A/B][256 rows x 128B] = 128 KiB. Row = 128B = 8 slots of 16B; swizzle
// phys_slot = (ks*4+kq) ^ (row&7) (byte addr = base ^ (ks<<6)) -- byte-identical to the
// 0-conflict pattern verified in rounds 1-3. Staged via inverse-swizzled global source.
// 2 barriers + 1 vmcnt gate per BK=128 tile (half the sync of the BK=64 structure);
// every MFMA cluster's operands are ds_read >=1 cluster earlier; reads 12/12 per phase.
//   P0: BAR | rd afB(mh1,ks0) | C1=afA*bP | rd afA(mh0,ks1) | stage B(t+2)->cur
//       | C2=afB*bP | rd afB(mh1,ks1) | vmcnt(4)
//   P1: BAR | C3=afA*bQ | rd afA<-A(t+1,mh0,ks0), bP<-B(t+1,ks0) | stage A(t+2)->cur
//       | C4=afB*bQ | rd bQ<-B(t+1,ks1)   [bQ overwritten only after C4]
// Ledger: gate sees {B(t+1):4, A(t+1):4, B(t+2):4}; vmcnt(4) drains exactly the t+1
// data P1 pre-reads (issued >=1 phase earlier), leaves B(t+2) in flight.
__global__ __launch_bounds__(512, 2)
void gemm_i8_bk128(const signed char* __restrict__ A,   // [M][K] i8
                   const signed char* __restrict__ B,   // [N][K] i8
                   const float* __restrict__ sx,        // [M]
                   const float* __restrict__ sw,        // [N]
                   const float* __restrict__ wscale_p,  // [1]
                   const float* __restrict__ bias,      // [N]
                   float* __restrict__ C,               // [M][N] fp32
                   int Nn, int Kk, int NT) {
  __shared__ signed char lds[2][2][256 * 128];

  const int tid  = threadIdx.x;
  const int lane = tid & 63;
  const int wave = tid >> 6;       // 0..7
  const int wr = wave >> 2;        // 0..1 (M)
  const int wc = wave & 3;         // 0..3 (N)

  // T1: XCD-aware swizzle (gridDim.x == 2048, divisible by 8)
  const int bid = blockIdx.x;
  const int cpx = gridDim.x >> 3;
  const int wg  = (bid & 7) * cpx + (bid >> 3);
  const int mt = wg / NT, nt = wg % NT;
  const int m0 = mt * 256, n0 = nt * 256;

  // staging: per gload instr, 64 lanes = 8 rows x 128B; lane l -> row l>>3, slot l&7
  const int srow = lane >> 3;
  const int ss   = (lane & 7) ^ (srow & 7);   // inverse-swizzled source k-slot
  const int r16  = lane & 15;
  const int kq   = lane >> 4;

  // per-thread global staging bases (wave covers rows wave*32 .. +31, 4 gloads x 8 rows)
  const signed char* ga = A + ((size_t)m0 + wave * 32 + srow) * Kk + ss * 16;
  const signed char* gb = B + ((size_t)n0 + wave * 32 + srow) * Kk + ss * 16;

  // fragment byte offsets: row*128 + ((kq ^ (row&7))<<4); ks=1 flips byte bit 6
  const int aoff = (wr * 128 + r16) * 128 + ((kq ^ (r16 & 7)) << 4);
  const int boff = (wc * 64  + r16) * 128 + ((kq ^ (r16 & 7)) << 4);

  i32x4 acc[8][4];
#pragma unroll
  for (int i = 0; i < 8; ++i)
#pragma unroll
    for (int j = 0; j < 4; ++j)
      acc[i][j] = (i32x4){0, 0, 0, 0};

  i32x4 afA[4], afB[4];   // A frag sets (roles rotate across clusters)
  i32x4 bP[4], bQ[4];     // B frags ks0 / ks1

  // stage one operand tile (32KB, 4 gloads/wave): op (0=A,1=B) -> lds[bfi], k-tile kt
#define STAGE128(bfi_, op_, kt_) do {                                           \
    const signed char* _g = ((op_) ? gb : ga) + (size_t)(kt_) * 128;            \
    signed char* _d = &lds[bfi_][op_][wave * 32 * 128];                         \
    GLD_LDS16(_g,                    _d);                                       \
    GLD_LDS16(_g + (size_t)8  * Kk,  _d + 1024);                                \
    GLD_LDS16(_g + (size_t)16 * Kk,  _d + 2048);                                \
    GLD_LDS16(_g + (size_t)24 * Kk,  _d + 3072);                                \
  } while (0)

#define LDFA(AF_, la_, mh_, ks_) do {                                           \
    _Pragma("unroll") for (int _i = 0; _i < 4; ++_i)                            \
      AF_[_i] = *reinterpret_cast<const i32x4*>(                                \
          (la_) + ((aoff + ((mh_) * 4 + _i) * 2048) ^ ((ks_) << 6)));           \
  } while (0)

#define LDFB(BF_, lb_, ks_) do {                                                \
    _Pragma("unroll") for (int _n = 0; _n < 4; ++_n)                            \
      BF_[_n] = *reinterpret_cast<const i32x4*>(                                \
          (lb_) + ((boff + _n * 2048) ^ ((ks_) << 6)));                         \
  } while (0)

#define MFMAC(mh_, AF_, BF_)                                                    \
  _Pragma("unroll") for (int i = 0; i < 4; ++i)                                 \
  _Pragma("unroll") for (int n = 0; n < 4; ++n)                                 \
    acc[(mh_) * 4 + i][n] = __builtin_amdgcn_mfma_i32_16x16x64_i8(              \
        AF_[i], BF_[n], acc[(mh_) * 4 + i][n], 0, 0, 0)

  const int KT = Kk >> 7;   // K/128 = 32

  // ---- prologue: t0->buf0, t1->buf1 (A then B each); drain t0; pre-read t0 frags ----
  STAGE128(0, 0, 0); STAGE128(0, 1, 0);
  STAGE128(1, 0, 1); STAGE128(1, 1, 1);
  asm volatile("s_waitcnt vmcnt(8)" ::: "memory");
  SCHED0(); BAR(); SCHED0();
  LDFA(afA, (const signed char*)&lds[0][0][0], 0, 0);
  LDFB(bP,  (const signed char*)&lds[0][1][0], 0);
  LDFB(bQ,  (const signed char*)&lds[0][1][0], 1);

#define TILE128(t_, CUR_) do {                                                  \
    const signed char* laC = &lds[CUR_][0][0];                                  \
    const signed char* laN = &lds[(CUR_) ^ 1][0][0];                            \
    const signed char* lbN = &lds[(CUR_) ^ 1][1][0];                            \
    const int kt2 = ((t_) + 2 < KT) ? (t_) + 2 : KT - 1;                        \
    /* P0 */                                                                    \
    SCHED0(); BAR(); SCHED0();                                                  \
    LDFA(afB, laC, 1, 0);                                                       \
    PRIO(1); MFMAC(0, afA, bP); PRIO(0);      /* C1: mh0,ks0 */                 \
    LDFA(afA, laC, 0, 1);                                                       \
    STAGE128(CUR_, 1, kt2);                                                     \
    PRIO(1); MFMAC(1, afB, bP); PRIO(0);      /* C2: mh1,ks0 */                 \
    LDFA(afB, laC, 1, 1);                                                       \
    SCHED0();                                                                   \
    asm volatile("s_waitcnt vmcnt(4)" ::: "memory");                            \
    /* P1 */                                                                    \
    SCHED0(); BAR(); SCHED0();                                                  \
    PRIO(1); MFMAC(0, afA, bQ); PRIO(0);      /* C3: mh0,ks1 */                 \
    LDFA(afA, laN, 0, 0);                                                       \
    LDFB(bP, lbN, 0);                                                           \
    STAGE128(CUR_, 0, kt2);                                                     \
    PRIO(1); MFMAC(1, afB, bQ); PRIO(0);      /* C4: mh1,ks1 */                 \
    LDFB(bQ, lbN, 1);                         /* bQ dead only after C4 */       \
  } while (0)

  for (int t = 0; t < KT; t += 2) {
    TILE128(t,     0);
    TILE128(t + 1, 1);
  }

  // ---- epilogue: out = acc * sx[row] * (sw[col]*wscale) + bias ----
  const float wsc = wscale_p[0];
  float cw[4], bv[4];
#pragma unroll
  for (int ni = 0; ni < 4; ++ni) {
    const int col = n0 + wc * 64 + ni * 16 + r16;
    cw[ni] = sw[col] * wsc;
    bv[ni] = bias[col];
  }
#pragma unroll
  for (int mi = 0; mi < 8; ++mi) {
#pragma unroll
    for (int r = 0; r < 4; ++r) {
      // C/D layout (16x16 shapes, dtype-independent): col = lane&15, row = (lane>>4)*4 + reg
      const int row = m0 + wr * 128 + mi * 16 + kq * 4 + r;
      const float sxr = sx[row];
      float* cp = C + (size_t)row * Nn + (n0 + wc * 64 + r16);
#pragma unroll
      for (int ni = 0; ni < 4; ++ni)
        cp[ni * 16] = (float)acc[mi][ni][r] * (sxr * cw[ni]) + bv[ni];
    }
  }
#undef STAGE128
#undef LDFA
#undef LDFB
#undef MFMAC
#undef TILE128
}

extern "C" void kernel_launch(void* const* d_in, const int* in_sizes, int n_in,
                              void* d_out, int out_size, void* d_ws, size_t ws_size,
                              hipStream_t stream) {
  (void)n_in; (void)out_size; (void)ws_size;
  const float* x  = (const float*)d_in[0];   // [M][K] fp32
  const float* w  = (const float*)d_in[1];   // [N][K] fp32 (fp8-representable values)
  const float* sc = (const float*)d_in[2];   // [1]
  const float* bs = (const float*)d_in[3];   // [N]
  float* out = (float*)d_out;                // [M][N] fp32

  const int N = in_sizes[3];        // 16384
  const int K = in_sizes[1] / N;    // 4096
  const int M = in_sizes[0] / K;    // 8192

  signed char* xq = (signed char*)d_ws;            // [M][K] i8  (32 MB)
  signed char* wq = xq + (size_t)M * K;            // [N][K] i8  (64 MB)
  float* sxp = (float*)(wq + (size_t)N * K);       // [M]
  float* swp = sxp + M;                            // [N]

  quant_rows<<<M + N, 256, 0, stream>>>(x, w, xq, wq, sxp, swp, M, M + N, K);

  const int NT = N / 256;
  const int nwg = (M / 256) * NT;                  // 2048, % 8 == 0
  gemm_i8_bk128<<<nwg, 512, 0, stream>>>(xq, wq, sxp, swp, sc, bs, out, N, K, NT);
}

// Round 10
// 627.225 us; speedup vs baseline: 13.1112x; 1.0059x over previous
//
#include <hip/hip_runtime.h>
#include <stdint.h>

typedef unsigned int u32;
using i32x4 = __attribute__((ext_vector_type(4))) int;

// async global->LDS, 16B per lane, dest = wave-uniform base + lane*16
#define GLD_LDS16(SRC, DST)                                      \
  __builtin_amdgcn_global_load_lds(                              \
      (const __attribute__((address_space(1))) void*)(SRC),      \
      (__attribute__((address_space(3))) void*)(DST), 16, 0, 0)

#define SCHED0() __builtin_amdgcn_sched_barrier(0)
#define SGB(m_, n_) __builtin_amdgcn_sched_group_barrier(m_, n_, 0)
#define BAR()    __builtin_amdgcn_s_barrier()
#define PRIO(x)  __builtin_amdgcn_s_setprio(x)

// ---------- pass 1: per-row symmetric int8 quant (x rows, then w rows) ----------
__global__ __launch_bounds__(256)
void quant_rows(const float* __restrict__ x, const float* __restrict__ w,
                signed char* __restrict__ xq, signed char* __restrict__ wq,
                float* __restrict__ sx, float* __restrict__ sw,
                int Mrows, int totRows, int K) {
  __shared__ float red[4];
  for (int row = blockIdx.x; row < totRows; row += gridDim.x) {
    const bool isx = row < Mrows;
    const float* src = isx ? x + (size_t)row * K : w + (size_t)(row - Mrows) * K;
    const float4* s4 = reinterpret_cast<const float4*>(src) + threadIdx.x * 4;
    float4 v[4];
#pragma unroll
    for (int g = 0; g < 4; ++g) v[g] = s4[g];
    float am = 0.f;
#pragma unroll
    for (int g = 0; g < 4; ++g)
      am = fmaxf(am, fmaxf(fmaxf(fabsf(v[g].x), fabsf(v[g].y)),
                           fmaxf(fabsf(v[g].z), fabsf(v[g].w))));
#pragma unroll
    for (int m = 1; m <= 32; m <<= 1) am = fmaxf(am, __shfl_xor(am, m));
    if ((threadIdx.x & 63) == 0) red[threadIdx.x >> 6] = am;
    __syncthreads();
    am = fmaxf(fmaxf(red[0], red[1]), fmaxf(red[2], red[3]));
    const float s   = am > 0.f ? am * (1.f / 127.f) : 1.f;
    const float inv = am > 0.f ? 127.f / am : 0.f;
    u32 pk[4];
#pragma unroll
    for (int g = 0; g < 4; ++g) {
      const float* vp = reinterpret_cast<const float*>(&v[g]);
      u32 p = 0;
#pragma unroll
      for (int e = 0; e < 4; ++e) {
        int q = (int)rintf(vp[e] * inv);
        q = q < -127 ? -127 : (q > 127 ? 127 : q);
        p |= ((u32)(q & 0xff)) << (8 * e);
      }
      pk[g] = p;
    }
    signed char* dst = (isx ? xq + (size_t)row * K : wq + (size_t)(row - Mrows) * K)
                       + threadIdx.x * 16;
    *reinterpret_cast<uint4*>(dst) = make_uint4(pk[0], pk[1], pk[2], pk[3]);
    if (threadIdx.x == 0) { if (isx) sx[row] = s; else sw[row - Mrows] = s; }
    __syncthreads();
  }
}

// ---------- pass 2: int8 GEMM BK=128 + T19 MFMA:ds_read mesh ----------
// Structure, addressing, swizzle, ledger: byte-identical to the verified round-9
// kernel (absmax bit-stable 0.1015625, 0 bank conflicts). Only change: program
// order + sched_group_barrier recipes so ds_reads/gloads emit INTERLEAVED with the
// MFMA stream. Serial model was tile = MFMA(2612) + LDS(2304); the mesh lets the
// 2 waves/SIMD slide into anti-phase (one reads while the other MFMAs).
// Region 1 (BAR..vmcnt gate): C1(afA*bP) mesh{afB<-A(t,1,0)} ; C2(afB*bP)
//   mesh{afA<-A(t,0,1), stage B(t+2)->cur} ; tail afB'<-A(t,1,1) ; vmcnt(4)
// Region 2 (BAR..end): C3(afA*bQ) mesh{bP<-B(t+1,ks0), stage A(t+2)->cur} ;
//   C4(afB*bQ) mesh{afA<-A(t+1,0,0)} ; tail bQ<-B(t+1,ks1)
// Gate ledger (unchanged): at gate outstanding = {B(t+1):4, A(t+1):4, B(t+2):4};
// vmcnt(4) drains the tile-old 8, leaves B(t+2) in flight.
__global__ __launch_bounds__(512, 2)
void gemm_i8_mesh(const signed char* __restrict__ A,   // [M][K] i8
                  const signed char* __restrict__ B,   // [N][K] i8
                  const float* __restrict__ sx,        // [M]
                  const float* __restrict__ sw,        // [N]
                  const float* __restrict__ wscale_p,  // [1]
                  const float* __restrict__ bias,      // [N]
                  float* __restrict__ C,               // [M][N] fp32
                  int Nn, int Kk, int NT) {
  __shared__ signed char lds[2][2][256 * 128];

  const int tid  = threadIdx.x;
  const int lane = tid & 63;
  const int wave = tid >> 6;       // 0..7
  const int wr = wave >> 2;        // 0..1 (M)
  const int wc = wave & 3;         // 0..3 (N)

  // T1: XCD-aware swizzle (gridDim.x == 2048, divisible by 8)
  const int bid = blockIdx.x;
  const int cpx = gridDim.x >> 3;
  const int wg  = (bid & 7) * cpx + (bid >> 3);
  const int mt = wg / NT, nt = wg % NT;
  const int m0 = mt * 256, n0 = nt * 256;

  // staging: per gload instr, 64 lanes = 8 rows x 128B; lane l -> row l>>3, slot l&7
  const int srow = lane >> 3;
  const int ss   = (lane & 7) ^ (srow & 7);   // inverse-swizzled source k-slot
  const int r16  = lane & 15;
  const int kq   = lane >> 4;

  const signed char* ga = A + ((size_t)m0 + wave * 32 + srow) * Kk + ss * 16;
  const signed char* gb = B + ((size_t)n0 + wave * 32 + srow) * Kk + ss * 16;

  // fragment byte offsets: row*128 + ((kq ^ (row&7))<<4); ks=1 flips byte bit 6
  const int aoff = (wr * 128 + r16) * 128 + ((kq ^ (r16 & 7)) << 4);
  const int boff = (wc * 64  + r16) * 128 + ((kq ^ (r16 & 7)) << 4);

  i32x4 acc[8][4];
#pragma unroll
  for (int i = 0; i < 8; ++i)
#pragma unroll
    for (int j = 0; j < 4; ++j)
      acc[i][j] = (i32x4){0, 0, 0, 0};

  i32x4 afA[4], afB[4];   // A frag sets (roles rotate across clusters)
  i32x4 bP[4], bQ[4];     // B frags ks0 / ks1

#define STAGE128(bfi_, op_, kt_) do {                                           \
    const signed char* _g = ((op_) ? gb : ga) + (size_t)(kt_) * 128;            \
    signed char* _d = &lds[bfi_][op_][wave * 32 * 128];                         \
    GLD_LDS16(_g,                    _d);                                       \
    GLD_LDS16(_g + (size_t)8  * Kk,  _d + 1024);                                \
    GLD_LDS16(_g + (size_t)16 * Kk,  _d + 2048);                                \
    GLD_LDS16(_g + (size_t)24 * Kk,  _d + 3072);                                \
  } while (0)

#define LDFA(AF_, la_, mh_, ks_) do {                                           \
    _Pragma("unroll") for (int _i = 0; _i < 4; ++_i)                            \
      AF_[_i] = *reinterpret_cast<const i32x4*>(                                \
          (la_) + ((aoff + ((mh_) * 4 + _i) * 2048) ^ ((ks_) << 6)));           \
  } while (0)

#define LDFB(BF_, lb_, ks_) do {                                                \
    _Pragma("unroll") for (int _n = 0; _n < 4; ++_n)                            \
      BF_[_n] = *reinterpret_cast<const i32x4*>(                                \
          (lb_) + ((boff + _n * 2048) ^ ((ks_) << 6)));                         \
  } while (0)

#define MFMAC(mh_, AF_, BF_)                                                    \
  _Pragma("unroll") for (int i = 0; i < 4; ++i)                                 \
  _Pragma("unroll") for (int n = 0; n < 4; ++n)                                 \
    acc[(mh_) * 4 + i][n] = __builtin_amdgcn_mfma_i32_16x16x64_i8(              \
        AF_[i], BF_[n], acc[(mh_) * 4 + i][n], 0, 0, 0)

  // T19 recipes (masks: MFMA=0x8, DS_READ=0x100, VMEM=0x10)
#define SGB_R1() do {                                                           \
    _Pragma("unroll") for (int _q = 0; _q < 4; ++_q) { SGB(0x8,3); SGB(0x100,1); } \
    SGB(0x8,4);                                                                 \
    _Pragma("unroll") for (int _q = 0; _q < 4; ++_q) { SGB(0x8,2); SGB(0x100,1); SGB(0x10,1); } \
    SGB(0x8,8); SGB(0x100,4);                                                   \
  } while (0)
#define SGB_R2() do {                                                           \
    _Pragma("unroll") for (int _q = 0; _q < 4; ++_q) { SGB(0x8,2); SGB(0x100,1); SGB(0x10,1); } \
    SGB(0x8,8);                                                                 \
    _Pragma("unroll") for (int _q = 0; _q < 4; ++_q) { SGB(0x8,3); SGB(0x100,1); } \
    SGB(0x8,4); SGB(0x100,4);                                                   \
  } while (0)

  const int KT = Kk >> 7;   // K/128 = 32

  // ---- prologue: t0->buf0, t1->buf1; drain t0; pre-read t0 frags ----
  STAGE128(0, 0, 0); STAGE128(0, 1, 0);
  STAGE128(1, 0, 1); STAGE128(1, 1, 1);
  asm volatile("s_waitcnt vmcnt(8)" ::: "memory");
  SCHED0(); BAR(); SCHED0();
  LDFA(afA, (const signed char*)&lds[0][0][0], 0, 0);
  LDFB(bP,  (const signed char*)&lds[0][1][0], 0);
  LDFB(bQ,  (const signed char*)&lds[0][1][0], 1);

#define TILE128(t_, CUR_) do {                                                  \
    const signed char* laC = &lds[CUR_][0][0];                                  \
    const signed char* laN = &lds[(CUR_) ^ 1][0][0];                            \
    const signed char* lbN = &lds[(CUR_) ^ 1][1][0];                            \
    const int kt2 = ((t_) + 2 < KT) ? (t_) + 2 : KT - 1;                        \
    /* ---- region 1: C1 + C2, meshed ---- */                                   \
    SCHED0(); BAR();                                                            \
    PRIO(1);                                                                    \
    LDFA(afB, laC, 1, 0);                     /* mesh: C2 operand */            \
    MFMAC(0, afA, bP);                        /* C1 */                          \
    LDFA(afA, laC, 0, 1);                     /* mesh: C3 operand */            \
    STAGE128(CUR_, 1, kt2);                   /* mesh: B(t+2)->cur */           \
    MFMAC(1, afB, bP);                        /* C2 */                          \
    LDFA(afB, laC, 1, 1);                     /* tail: C4 operand */            \
    SGB_R1();                                                                   \
    PRIO(0);                                                                    \
    asm volatile("s_waitcnt vmcnt(4)" ::: "memory");                            \
    /* ---- region 2: C3 + C4, meshed ---- */                                   \
    SCHED0(); BAR();                                                            \
    PRIO(1);                                                                    \
    LDFB(bP, lbN, 0);                         /* mesh: next C1/C2 operand */    \
    STAGE128(CUR_, 0, kt2);                   /* mesh: A(t+2)->cur */           \
    MFMAC(0, afA, bQ);                        /* C3 */                          \
    LDFA(afA, laN, 0, 0);                     /* mesh: next C1 operand */       \
    MFMAC(1, afB, bQ);                        /* C4 */                          \
    LDFB(bQ, lbN, 1);                         /* tail: next C3/C4 operand */    \
    SGB_R2();                                                                   \
    PRIO(0);                                                                    \
  } while (0)

  for (int t = 0; t < KT; t += 2) {
    TILE128(t,     0);
    TILE128(t + 1, 1);
  }

  // ---- epilogue: out = acc * sx[row] * (sw[col]*wscale) + bias ----
  const float wsc = wscale_p[0];
  float cw[4], bv[4];
#pragma unroll
  for (int ni = 0; ni < 4; ++ni) {
    const int col = n0 + wc * 64 + ni * 16 + r16;
    cw[ni] = sw[col] * wsc;
    bv[ni] = bias[col];
  }
#pragma unroll
  for (int mi = 0; mi < 8; ++mi) {
#pragma unroll
    for (int r = 0; r < 4; ++r) {
      // C/D layout (16x16 shapes, dtype-independent): col = lane&15, row = (lane>>4)*4 + reg
      const int row = m0 + wr * 128 + mi * 16 + kq * 4 + r;
      const float sxr = sx[row];
      float* cp = C + (size_t)row * Nn + (n0 + wc * 64 + r16);
#pragma unroll
      for (int ni = 0; ni < 4; ++ni)
        cp[ni * 16] = (float)acc[mi][ni][r] * (sxr * cw[ni]) + bv[ni];
    }
  }
#undef STAGE128
#undef LDFA
#undef LDFB
#undef MFMAC
#undef SGB_R1
#undef SGB_R2
#undef TILE128
}

extern "C" void kernel_launch(void* const* d_in, const int* in_sizes, int n_in,
                              void* d_out, int out_size, void* d_ws, size_t ws_size,
                              hipStream_t stream) {
  (void)n_in; (void)out_size; (void)ws_size;
  const float* x  = (const float*)d_in[0];   // [M][K] fp32
  const float* w  = (const float*)d_in[1];   // [N][K] fp32 (fp8-representable values)
  const float* sc = (const float*)d_in[2];   // [1]
  const float* bs = (const float*)d_in[3];   // [N]
  float* out = (float*)d_out;                // [M][N] fp32

  const int N = in_sizes[3];        // 16384
  const int K = in_sizes[1] / N;    // 4096
  const int M = in_sizes[0] / K;    // 8192

  signed char* xq = (signed char*)d_ws;            // [M][K] i8  (32 MB)
  signed char* wq = xq + (size_t)M * K;            // [N][K] i8  (64 MB)
  float* sxp = (float*)(wq + (size_t)N * K);       // [M]
  float* swp = sxp + M;                            // [N]

  quant_rows<<<M + N, 256, 0, stream>>>(x, w, xq, wq, sxp, swp, M, M + N, K);

  const int NT = N / 256;
  const int nwg = (M / 256) * NT;                  // 2048, % 8 == 0
  gemm_i8_mesh<<<nwg, 512, 0, stream>>>(xq, wq, sxp, swp, sc, bs, out, N, K, NT);
}